// Round 1
// baseline (422.999 us; speedup 1.0000x reference)
//
#include <hip/hip_runtime.h>
#include <hip/hip_bf16.h>
#include <stdint.h>

// Problem constants
#define Bdim 4
#define Sdim 2048
#define Edim 1024
#define Hdim 16
#define Ddim 64
#define SCALE 0.03125f      // 1/sqrt(E) = 1/32
#define NEG_INF (-1e20f)

typedef __attribute__((ext_vector_type(8))) short bf16x8;
typedef __attribute__((ext_vector_type(4))) float f32x4;

__device__ __forceinline__ short f2bf(float f) {
    __hip_bfloat16 h = __float2bfloat16(f);
    return *reinterpret_cast<short*>(&h);
}

// async global->LDS, 16B per lane. LDS dest must be wave-uniform base + lane*16
// (our staging uses lds_off = tid*16, which satisfies this).
__device__ __forceinline__ void async16(void* lds, const void* g) {
    __builtin_amdgcn_global_load_lds(
        (const __attribute__((address_space(1))) char*)g,
        (__attribute__((address_space(3))) char*)lds, 16, 0, 0);
}

// ---------------------------------------------------------------- casts
__global__ void cast_f32_bf16(const float* __restrict__ in, short* __restrict__ out, int n4) {
    int i = blockIdx.x * 256 + threadIdx.x;
    if (i >= n4) return;
    float4 v = reinterpret_cast<const float4*>(in)[i];
    short4 o;
    o.x = f2bf(v.x); o.y = f2bf(v.y); o.z = f2bf(v.z); o.w = f2bf(v.w);
    reinterpret_cast<short4*>(out)[i] = o;
}

__global__ void build_mask(const int* __restrict__ xr, float* __restrict__ mf) {
    int i = blockIdx.x * 256 + threadIdx.x;
    if (i < Bdim * Sdim) mf[i] = (xr[i] != 0) ? 0.0f : NEG_INF;
}

// ---------------------------------------------------------------- GEMM (NT)
// C[m,n] = sum_k A[m,k]*B[n,k] + bias[n];  A:[M,K] B:[N,K] row-major bf16, C bf16.
// 128x128 tile, BK=32, 4 waves (2x2), 16x16x32 MFMA. LDS rows are 64B (4 x 16B
// chunks); layout swizzle: chunk ^= (row&3); applied on the global SOURCE during
// global_load_lds staging and on the ds_read side (involution).
__global__ __launch_bounds__(256) void gemm_nt_bf16(
    const short* __restrict__ A, const short* __restrict__ B,
    const float* __restrict__ bias, short* __restrict__ C,
    int M, int N, int K)
{
    __shared__ __align__(16) char As[8192];
    __shared__ __align__(16) char Bs[8192];
    const int t = threadIdx.x;
    const int lane = t & 63, w = t >> 6;
    const int wm = w >> 1, wn = w & 1;
    const int lr = lane & 15, lg = lane >> 4;
    const int m0 = blockIdx.x * 128, n0 = blockIdx.y * 128;

    f32x4 acc[4][4];
#pragma unroll
    for (int i = 0; i < 4; i++)
#pragma unroll
        for (int j = 0; j < 4; j++) acc[i][j] = (f32x4){0.f, 0.f, 0.f, 0.f};

    // staging: o = pass*4096 + t*16; row = o/64 (64B rows), chunk = (o&63)/16
    const int o0 = t * 16, o1 = 4096 + t * 16;
    const int r0 = o0 >> 6, r1 = o1 >> 6;
    const int sb0 = ((((o0 >> 4) & 3) ^ (r0 & 3)) << 4);  // pre-swizzled src byte within row
    const int sb1 = ((((o1 >> 4) & 3) ^ (r1 & 3)) << 4);
    const char* Ab0 = (const char*)(A + (size_t)(m0 + r0) * K) + sb0;
    const char* Ab1 = (const char*)(A + (size_t)(m0 + r1) * K) + sb1;
    const char* Bb0 = (const char*)(B + (size_t)(n0 + r0) * K) + sb0;
    const char* Bb1 = (const char*)(B + (size_t)(n0 + r1) * K) + sb1;

    int aoff[4], boff[4];
#pragma unroll
    for (int i = 0; i < 4; i++) {
        int ra = wm * 64 + i * 16 + lr;
        aoff[i] = ra * 64 + ((lg ^ (ra & 3)) << 4);
        int rb = wn * 64 + i * 16 + lr;
        boff[i] = rb * 64 + ((lg ^ (rb & 3)) << 4);
    }

    for (int kt = 0; kt < K; kt += 32) {
        __syncthreads();
        async16(As + o0, Ab0 + kt * 2);
        async16(As + o1, Ab1 + kt * 2);
        async16(Bs + o0, Bb0 + kt * 2);
        async16(Bs + o1, Bb1 + kt * 2);
        __syncthreads();
        bf16x8 af[4], bfr[4];
#pragma unroll
        for (int i = 0; i < 4; i++) {
            af[i]  = *(const bf16x8*)(As + aoff[i]);
            bfr[i] = *(const bf16x8*)(Bs + boff[i]);
        }
#pragma unroll
        for (int i = 0; i < 4; i++)
#pragma unroll
            for (int j = 0; j < 4; j++)
                acc[i][j] = __builtin_amdgcn_mfma_f32_16x16x32_bf16(af[i], bfr[j], acc[i][j], 0, 0, 0);
    }

#pragma unroll
    for (int j = 0; j < 4; j++) {
        int col = n0 + wn * 64 + j * 16 + lr;
        float bv = bias[col];
#pragma unroll
        for (int i = 0; i < 4; i++) {
            int rowb = m0 + wm * 64 + i * 16 + lg * 4;
#pragma unroll
            for (int r = 0; r < 4; r++)
                C[(size_t)(rowb + r) * N + col] = f2bf(acc[i][j][r] + bv);
        }
    }
}

// ---------------------------------------------------------------- attention
// out[bh, kk, d] = softmax_qq( Kp[kk]·Qp[qq]*SCALE + mask[qq] ) @ Vp[qq, d]
// block: 4 waves, 64 kk rows (16 per wave), qq tiles of 64, online softmax.
// LDS tiles are [64 rows][128B] with chunk swizzle: byte ^= (row&7)<<4.
__global__ __launch_bounds__(256) void attn_fwd(
    const short* __restrict__ Qb, const short* __restrict__ Kb,
    const short* __restrict__ Vb, const float* __restrict__ maskf,
    float* __restrict__ out)
{
    __shared__ __align__(16) char Qs[8192];
    __shared__ __align__(16) char Vt[8192];
    __shared__ __align__(16) char Ps[8192];
    const int t = threadIdx.x, lane = t & 63, w = t >> 6;
    const int lr = lane & 15, lg = lane >> 4;
    const int kkt = blockIdx.x, bh = blockIdx.y;
    const int b = bh >> 4, h = bh & 15;

    // A-operand fragments: K-projection rows (the output rows), kept in regs.
    bf16x8 aK0, aK1;
    {
        int kkrow = kkt * 64 + w * 16 + lr;
        const short* kp = Kb + (size_t)(b * Sdim + kkrow) * Edim + h * Ddim;
        aK0 = *(const bf16x8*)(kp + lg * 8);
        aK1 = *(const bf16x8*)(kp + 32 + lg * 8);
    }

    float m_r[4], l_r[4];
    f32x4 accO[4];
#pragma unroll
    for (int r = 0; r < 4; r++) { m_r[r] = -INFINITY; l_r[r] = 0.f; }
#pragma unroll
    for (int d = 0; d < 4; d++) accO[d] = (f32x4){0.f, 0.f, 0.f, 0.f};

    // Q-tile staging precompute (global_load_lds, pre-swizzled source)
    const int o0 = t * 16, o1 = 4096 + t * 16;
    const int qr0 = o0 >> 7, qr1 = o1 >> 7;
    const int qb0 = ((((o0 >> 4) & 7) ^ (qr0 & 7)) << 4);
    const int qb1 = ((((o1 >> 4) & 7) ^ (qr1 & 7)) << 4);
    const char* Qsrc0 = (const char*)(Qb + (size_t)(b * Sdim + qr0) * Edim + h * Ddim) + qb0;
    const char* Qsrc1 = (const char*)(Qb + (size_t)(b * Sdim + qr1) * Edim + h * Ddim) + qb1;
    // V-tile: explicit transposed staging
    const int vqq = t & 63, vdc = (t >> 6) * 8;
    const short* Vsrc = Vb + (size_t)(b * Sdim + vqq) * Edim + h * Ddim + vdc;
    const float* mrow = maskf + b * Sdim;

    for (int j = 0; j < 32; j++) {
        __syncthreads();
        async16(Qs + o0, Qsrc0 + (size_t)j * 64 * Edim * 2);
        async16(Qs + o1, Qsrc1 + (size_t)j * 64 * Edim * 2);
#pragma unroll
        for (int r2 = 0; r2 < 2; r2++) {
            bf16x8 v = *(const bf16x8*)(Vsrc + (size_t)j * 64 * Edim + r2 * 32);
#pragma unroll
            for (int e = 0; e < 8; e++) {
                int d = vdc + r2 * 32 + e;
                int off = d * 128 + ((vqq * 2) ^ ((d & 7) << 4));
                *(short*)(Vt + off) = v[e];
            }
        }
        __syncthreads();

        // S = K·Q^T (per wave: 16 kk rows x 64 qq)
        f32x4 sfr[4];
#pragma unroll
        for (int sub = 0; sub < 4; sub++) {
            int rq = sub * 16 + lr;
            bf16x8 q0 = *(const bf16x8*)(Qs + rq * 128 + ((lg ^ (rq & 7)) << 4));
            bf16x8 q1 = *(const bf16x8*)(Qs + rq * 128 + (((lg + 4) ^ (rq & 7)) << 4));
            f32x4 z = (f32x4){0.f, 0.f, 0.f, 0.f};
            z = __builtin_amdgcn_mfma_f32_16x16x32_bf16(aK0, q0, z, 0, 0, 0);
            z = __builtin_amdgcn_mfma_f32_16x16x32_bf16(aK1, q1, z, 0, 0, 0);
            float mv = mrow[j * 64 + sub * 16 + lr];
#pragma unroll
            for (int r = 0; r < 4; r++) sfr[sub][r] = z[r] * SCALE + mv;
        }

        // online softmax over qq (C-layout columns); row r lives in 16-lane group
        float tmaxv[4], scal[4];
#pragma unroll
        for (int r = 0; r < 4; r++) {
            float tm = fmaxf(fmaxf(sfr[0][r], sfr[1][r]), fmaxf(sfr[2][r], sfr[3][r]));
#pragma unroll
            for (int off = 1; off < 16; off <<= 1) tm = fmaxf(tm, __shfl_xor(tm, off));
            tmaxv[r] = tm;
        }
#pragma unroll
        for (int r = 0; r < 4; r++) {
            float mn = fmaxf(m_r[r], tmaxv[r]);
            scal[r] = __expf(m_r[r] - mn);
            m_r[r] = mn;
        }
        float pfr[4][4];
#pragma unroll
        for (int sub = 0; sub < 4; sub++)
#pragma unroll
            for (int r = 0; r < 4; r++) pfr[sub][r] = __expf(sfr[sub][r] - m_r[r]);
#pragma unroll
        for (int r = 0; r < 4; r++) {
            float ts = pfr[0][r] + pfr[1][r] + pfr[2][r] + pfr[3][r];
#pragma unroll
            for (int off = 1; off < 16; off <<= 1) ts += __shfl_xor(ts, off);
            l_r[r] = l_r[r] * scal[r] + ts;
        }
#pragma unroll
        for (int d = 0; d < 4; d++)
#pragma unroll
            for (int r = 0; r < 4; r++) accO[d][r] *= scal[r];

        // P -> LDS (bf16, swizzled) to convert C-layout -> A-fragment layout
#pragma unroll
        for (int sub = 0; sub < 4; sub++)
#pragma unroll
            for (int r = 0; r < 4; r++) {
                int prow = w * 16 + lg * 4 + r;
                int off = prow * 128 + ((((sub * 16 + lr) * 2)) ^ ((prow & 7) << 4));
                *(short*)(Ps + off) = f2bf(pfr[sub][r]);
            }
        __syncthreads();

        // PV: accO[kk, d] += P · V   (A = P rows, B = Vt rows = V columns)
        int rowp = w * 16 + lr;
        bf16x8 pa0 = *(const bf16x8*)(Ps + rowp * 128 + ((lg ^ (rowp & 7)) << 4));
        bf16x8 pa1 = *(const bf16x8*)(Ps + rowp * 128 + (((lg + 4) ^ (rowp & 7)) << 4));
#pragma unroll
        for (int d = 0; d < 4; d++) {
            int rv = d * 16 + lr;
            bf16x8 v0 = *(const bf16x8*)(Vt + rv * 128 + ((lg ^ (rv & 7)) << 4));
            bf16x8 v1 = *(const bf16x8*)(Vt + rv * 128 + (((lg + 4) ^ (rv & 7)) << 4));
            accO[d] = __builtin_amdgcn_mfma_f32_16x16x32_bf16(pa0, v0, accO[d], 0, 0, 0);
            accO[d] = __builtin_amdgcn_mfma_f32_16x16x32_bf16(pa1, v1, accO[d], 0, 0, 0);
        }
    }

    // epilogue: out[(bh*S + kk)*D + d] = O / l   (reference's no-transpose reshape)
#pragma unroll
    for (int d = 0; d < 4; d++)
#pragma unroll
        for (int r = 0; r < 4; r++) {
            int row = kkt * 64 + w * 16 + lg * 4 + r;
            out[(size_t)(bh * Sdim + row) * Ddim + d * 16 + lr] = accO[d][r] / l_r[r];
        }
}

// ---------------------------------------------------------------- launch
extern "C" void kernel_launch(void* const* d_in, const int* in_sizes, int n_in,
                              void* d_out, int out_size, void* d_ws, size_t ws_size,
                              hipStream_t stream) {
    const float* x    = (const float*)d_in[0];
    const int*   xraw = (const int*)d_in[1];
    const float* Wq   = (const float*)d_in[2];
    const float* bq   = (const float*)d_in[3];
    const float* Wk   = (const float*)d_in[4];
    const float* bk   = (const float*)d_in[5];
    const float* Wv   = (const float*)d_in[6];
    const float* bv   = (const float*)d_in[7];
    float* out = (float*)d_out;
    char* ws = (char*)d_ws;

    // workspace layout (bytes)
    short* Xb    = (short*)(ws);                       // 16 MB
    short* Qbuf  = (short*)(ws + (size_t)16777216);    // 16 MB
    short* Kbuf  = (short*)(ws + (size_t)33554432);    // 16 MB
    short* Vbuf  = (short*)(ws + (size_t)50331648);    // 16 MB
    short* Wqb   = (short*)(ws + (size_t)67108864);    // 2 MB
    short* Wkb   = (short*)(ws + (size_t)69206016);    // 2 MB
    short* Wvb   = (short*)(ws + (size_t)71303168);    // 2 MB
    float* maskf = (float*)(ws + (size_t)73400320);    // 32 KB

    const int nX4 = (Bdim * Sdim * Edim) / 4;   // 2097152
    const int nW4 = (Edim * Edim) / 4;          // 262144

    cast_f32_bf16<<<(nX4 + 255) / 256, 256, 0, stream>>>(x, Xb, nX4);
    cast_f32_bf16<<<(nW4 + 255) / 256, 256, 0, stream>>>(Wq, Wqb, nW4);
    cast_f32_bf16<<<(nW4 + 255) / 256, 256, 0, stream>>>(Wk, Wkb, nW4);
    cast_f32_bf16<<<(nW4 + 255) / 256, 256, 0, stream>>>(Wv, Wvb, nW4);
    build_mask<<<(Bdim * Sdim) / 256, 256, 0, stream>>>(xraw, maskf);

    dim3 ggrid(64, 8);
    gemm_nt_bf16<<<ggrid, 256, 0, stream>>>(Xb, Wqb, bq, Qbuf, Bdim * Sdim, Edim, Edim);
    gemm_nt_bf16<<<ggrid, 256, 0, stream>>>(Xb, Wkb, bk, Kbuf, Bdim * Sdim, Edim, Edim);
    gemm_nt_bf16<<<ggrid, 256, 0, stream>>>(Xb, Wvb, bv, Vbuf, Bdim * Sdim, Edim, Edim);

    dim3 agrid(Sdim / 64, Bdim * Hdim);
    attn_fwd<<<agrid, 256, 0, stream>>>(Qbuf, Kbuf, Vbuf, maskf, out);
}

// Round 5
// 312.262 us; speedup vs baseline: 1.3546x; 1.3546x over previous
//
#include <hip/hip_runtime.h>
#include <hip/hip_bf16.h>
#include <stdint.h>

// Problem constants
#define Bdim 4
#define Sdim 2048
#define Edim 1024
#define Hdim 16
#define Ddim 64
#define SCALE 0.03125f      // 1/sqrt(E) = 1/32
#define NEG_INF (-1e20f)

typedef __attribute__((ext_vector_type(8))) short bf16x8;
typedef __attribute__((ext_vector_type(4))) float f32x4;
typedef __attribute__((ext_vector_type(16))) float f32x16;

__device__ __forceinline__ short f2bf(float f) {
    __hip_bfloat16 h = __float2bfloat16(f);
    return *reinterpret_cast<short*>(&h);
}
__device__ __forceinline__ unsigned pk2(float lo, float hi) {
    unsigned a = (unsigned short)f2bf(lo);
    unsigned b = (unsigned short)f2bf(hi);
    return a | (b << 16);
}

// async global->LDS, 16B per lane (dest = wave-uniform base + lane*16)
__device__ __forceinline__ void async16(void* lds, const void* g) {
    __builtin_amdgcn_global_load_lds(
        (const __attribute__((address_space(1))) char*)g,
        (__attribute__((address_space(3))) char*)lds, 16, 0, 0);
}

// ---------------------------------------------------------------- casts
__global__ void cast_f32_bf16(const float* __restrict__ in, short* __restrict__ out, int n4) {
    int i = blockIdx.x * 256 + threadIdx.x;
    if (i >= n4) return;
    float4 v = reinterpret_cast<const float4*>(in)[i];
    short4 o;
    o.x = f2bf(v.x); o.y = f2bf(v.y); o.z = f2bf(v.z); o.w = f2bf(v.w);
    reinterpret_cast<short4*>(out)[i] = o;
}

__global__ void build_mask(const int* __restrict__ xr, float* __restrict__ mf) {
    int i = blockIdx.x * 256 + threadIdx.x;
    if (i < Bdim * Sdim) mf[i] = (xr[i] != 0) ? 0.0f : NEG_INF;
}

// ---------------------------------------------------------------- GEMM (NT)
// C[m,n] = sum_k A[m,k]*B[n,k] + bias[n]. 128x128 tile, BK=32, 4 waves, 16x16x32.
// VT=0: C row-major [M][N] bf16.  VT=1: write Vt[(b*16+h)*64+d][s] (transposed per head).
template <int VT>
__global__ __launch_bounds__(256) void gemm_nt_bf16(
    const short* __restrict__ A, const short* __restrict__ B,
    const float* __restrict__ bias, short* __restrict__ C,
    int M, int N, int K)
{
    __shared__ __align__(16) char As[8192];
    __shared__ __align__(16) char Bs[8192];
    const int t = threadIdx.x;
    const int lane = t & 63, w = t >> 6;
    const int wm = w >> 1, wn = w & 1;
    const int lr = lane & 15, lg = lane >> 4;
    const int m0 = blockIdx.x * 128, n0 = blockIdx.y * 128;

    f32x4 acc[4][4];
#pragma unroll
    for (int i = 0; i < 4; i++)
#pragma unroll
        for (int j = 0; j < 4; j++) acc[i][j] = (f32x4){0.f, 0.f, 0.f, 0.f};

    const int o0 = t * 16, o1 = 4096 + t * 16;
    const int r0 = o0 >> 6, r1 = o1 >> 6;
    const int sb0 = ((((o0 >> 4) & 3) ^ (r0 & 3)) << 4);
    const int sb1 = ((((o1 >> 4) & 3) ^ (r1 & 3)) << 4);
    const char* Ab0 = (const char*)(A + (size_t)(m0 + r0) * K) + sb0;
    const char* Ab1 = (const char*)(A + (size_t)(m0 + r1) * K) + sb1;
    const char* Bb0 = (const char*)(B + (size_t)(n0 + r0) * K) + sb0;
    const char* Bb1 = (const char*)(B + (size_t)(n0 + r1) * K) + sb1;

    int aoff[4], boff[4];
#pragma unroll
    for (int i = 0; i < 4; i++) {
        int ra = wm * 64 + i * 16 + lr;
        aoff[i] = ra * 64 + ((lg ^ (ra & 3)) << 4);
        int rb = wn * 64 + i * 16 + lr;
        boff[i] = rb * 64 + ((lg ^ (rb & 3)) << 4);
    }

    for (int kt = 0; kt < K; kt += 32) {
        __syncthreads();
        async16(As + o0, Ab0 + kt * 2);
        async16(As + o1, Ab1 + kt * 2);
        async16(Bs + o0, Bb0 + kt * 2);
        async16(Bs + o1, Bb1 + kt * 2);
        __syncthreads();
        bf16x8 af[4], bfr[4];
#pragma unroll
        for (int i = 0; i < 4; i++) {
            af[i]  = *(const bf16x8*)(As + aoff[i]);
            bfr[i] = *(const bf16x8*)(Bs + boff[i]);
        }
#pragma unroll
        for (int i = 0; i < 4; i++)
#pragma unroll
            for (int j = 0; j < 4; j++)
                acc[i][j] = __builtin_amdgcn_mfma_f32_16x16x32_bf16(af[i], bfr[j], acc[i][j], 0, 0, 0);
    }

#pragma unroll
    for (int j = 0; j < 4; j++) {
        int col = n0 + wn * 64 + j * 16 + lr;
        float bv = bias[col];
#pragma unroll
        for (int i = 0; i < 4; i++) {
            int rowb = m0 + wm * 64 + i * 16 + lg * 4;
#pragma unroll
            for (int r = 0; r < 4; r++) {
                int row = rowb + r;
                if (VT) {
                    size_t vtr = (size_t)(((row >> 11) * 16 + (col >> 6)) * 64 + (col & 63));
                    C[vtr * (size_t)Sdim + (row & 2047)] = f2bf(acc[i][j][r] + bv);
                } else {
                    C[(size_t)row * N + col] = f2bf(acc[i][j][r] + bv);
                }
            }
        }
    }
}

// ---------------------------------------------------------------- attention v3
// out[bh, kk, d] = softmax_qq( K[kk]·Q[qq]*SCALE + mask[qq] ) @ V[qq, d]
// 8 waves x 32 kk rows = 256 kk per block. qq tiles of 64 (2 subtiles of 32).
// QK: mfma_32x32x16(A=Q, B=K)  -> C[qq][kk], kk = lane&31 (stats lane-local)
// PV: mfma_32x32x16(A=Vt, B=P) -> C[d][kk],  kk = lane&31 (rescale lane-local)
// Cross-hi exchange exclusively via __shfl_xor(...,32) (compiler-guaranteed
// semantics; no raw permlane asm -> no direction assumption).
__global__ __launch_bounds__(512, 4) void attn_fwd2(
    const short* __restrict__ Qb, const short* __restrict__ Kb,
    const short* __restrict__ VtG, const float* __restrict__ maskf,
    float* __restrict__ out)
{
    __shared__ __align__(16) char QsA[8192];
    __shared__ __align__(16) char VsA[8192];
    __shared__ __align__(16) char QsB[8192];
    __shared__ __align__(16) char VsB[8192];
    __shared__ __align__(16) float mlds[2048];

    const int t = threadIdx.x;
    const int lane = t & 63, w = t >> 6;
    const int l31 = lane & 31, hi = lane >> 5;
    const int bh = blockIdx.y;
    const int b = bh >> 4, h = bh & 15;
    const int kkw = blockIdx.x * 256 + w * 32;

    // K fragments (B operand of QK), 4 d-chunks (d = ch*16 + hi*8 + e)
    bf16x8 kf[4];
    {
        const short* kp = Kb + (size_t)(b * Sdim + kkw + l31) * Edim + h * Ddim + hi * 8;
#pragma unroll
        for (int ch = 0; ch < 4; ch++) kf[ch] = *(const bf16x8*)(kp + ch * 16);
    }

    // stage full mask row for this b (8KB)
    async16((char*)mlds + t * 16, (const char*)(maskf + b * Sdim) + t * 16);

    // staging source precompute (thread t fills LDS offset t*16)
    const int o = t * 16;
    const int sub_s = o >> 12, blk_s = (o >> 9) & 7, l_s = (o >> 4) & 31;
    const int q_qq = sub_s * 32 + l_s;
    const int q_d  = (blk_s >> 1) * 16 + (blk_s & 1) * 8;
    const char* qsrc = (const char*)(Qb + (size_t)(b * Sdim + q_qq) * Edim + h * Ddim + q_d);
    const int v_d = (blk_s & 1) * 32 + l_s;
    const int v_q = sub_s * 32 + (blk_s >> 1) * 8;
    const char* vsrc = (const char*)(VtG + (size_t)(bh * Ddim + v_d) * Sdim + v_q);

    // prologue: stage tile 0 into buffer A
    async16(QsA + o, qsrc);
    async16(VsA + o, vsrc);

    f32x16 accO0, accO1;
#pragma unroll
    for (int r = 0; r < 16; r++) { accO0[r] = 0.f; accO1[r] = 0.f; }
    float m_run = -INFINITY, l_run = 0.f;

    for (int j = 0; j < 32; j++) {
        const int cur = j & 1;
        char* qcur = cur ? QsB : QsA;
        char* vcur = cur ? VsB : VsA;
        char* qnxt = cur ? QsA : QsB;
        char* vnxt = cur ? VsA : VsB;
        const int jn = (j + 1) & 31;
        async16(qnxt + o, qsrc + (size_t)jn * 64 * Edim * 2);
        async16(vnxt + o, vsrc + (size_t)jn * 64 * 2);
        asm volatile("s_waitcnt vmcnt(2)" ::: "memory");
        __builtin_amdgcn_s_barrier();

#pragma unroll
        for (int sub = 0; sub < 2; sub++) {
            const char* qbase = qcur + sub * 4096;
            const char* vbase = vcur + sub * 4096;
            // ---- QK^T
            f32x16 s;
#pragma unroll
            for (int r = 0; r < 16; r++) s[r] = 0.f;
#pragma unroll
            for (int ch = 0; ch < 4; ch++) {
                bf16x8 qf = *(const bf16x8*)(qbase + (ch * 2 + hi) * 512 + l31 * 16);
                s = __builtin_amdgcn_mfma_f32_32x32x16_bf16(qf, kf[ch], s, 0, 0, 0);
            }
            // ---- scale + mask (C reg g*4+q -> qq = q + 8g + 4hi)
            const int qt = j * 64 + sub * 32;
#pragma unroll
            for (int g = 0; g < 4; g++) {
                f32x4 mv = *(const f32x4*)(mlds + qt + 8 * g + 4 * hi);
#pragma unroll
                for (int q = 0; q < 4; q++)
                    s[g * 4 + q] = s[g * 4 + q] * SCALE + mv[q];
            }
            // ---- tile max: 16 in-lane + cross-hi via shfl_xor(32)
            float tm = s[0];
#pragma unroll
            for (int r = 1; r < 16; r++) tm = fmaxf(tm, s[r]);
            tm = fmaxf(tm, __shfl_xor(tm, 32));
            // ---- classic online-softmax rescale (always)
            {
                float mnew = fmaxf(m_run, tm);
                float scal = __expf(m_run - mnew);
                l_run *= scal;
#pragma unroll
                for (int r = 0; r < 16; r++) { accO0[r] *= scal; accO1[r] *= scal; }
                m_run = mnew;
            }
            // ---- P = exp(s - m), row-sum, pack to bf16 pairs
            // wq[g*2+w] = pk(P[qq=8g+4hi+2w], P[qq=8g+4hi+2w+1])
            float ts = 0.f;
            unsigned wq[8];
#pragma unroll
            for (int g = 0; g < 4; g++) {
                float p0 = __expf(s[g * 4 + 0] - m_run);
                float p1 = __expf(s[g * 4 + 1] - m_run);
                float p2 = __expf(s[g * 4 + 2] - m_run);
                float p3 = __expf(s[g * 4 + 3] - m_run);
                ts += (p0 + p1) + (p2 + p3);
                wq[g * 2 + 0] = pk2(p0, p1);
                wq[g * 2 + 1] = pk2(p2, p3);
            }
            ts += __shfl_xor(ts, 32);
            l_run += ts;
            // ---- PV per 16-qq chunk c. B-frag word j of lane (l31,hi) needs
            // P[qq = c*16 + hi*8 + 2j..+1][kk=l31], i.e. source lane hi_src=j>>1,
            // register wq[2*(2c+hi) + (j&1)]. Exchange via shfl_xor(32) z-trick:
            //   v0 = wq[4c+w] (hi=0's g=2c word), v1 = wq[4c+2+w] (hi=1's g=2c+1 word)
            //   z = hi ? v0 : v1 ; p = shfl_xor(z,32)
            //   u[w] = hi ? p : v0 ; u[2+w] = hi ? v1 : p
#pragma unroll
            for (int c = 0; c < 2; c++) {
                union { unsigned u[4]; bf16x8 v; } pf;
#pragma unroll
                for (int ww = 0; ww < 2; ww++) {
                    unsigned v0 = wq[4 * c + ww];
                    unsigned v1 = wq[4 * c + 2 + ww];
                    unsigned z = hi ? v0 : v1;
                    unsigned p = __shfl_xor(z, 32);
                    pf.u[ww]     = hi ? p : v0;
                    pf.u[2 + ww] = hi ? v1 : p;
                }
                {
                    bf16x8 vf = *(const bf16x8*)(vbase + ((c * 2 + hi) * 2 + 0) * 512 + l31 * 16);
                    accO0 = __builtin_amdgcn_mfma_f32_32x32x16_bf16(vf, pf.v, accO0, 0, 0, 0);
                }
                {
                    bf16x8 vf = *(const bf16x8*)(vbase + ((c * 2 + hi) * 2 + 1) * 512 + l31 * 16);
                    accO1 = __builtin_amdgcn_mfma_f32_32x32x16_bf16(vf, pf.v, accO1, 0, 0, 0);
                }
            }
        }
        __builtin_amdgcn_s_barrier();
    }

    // epilogue: out[(bh*S + kk)*64 + d] = accO / l ; kk = lane&31 (lane-local l)
    const float inv = 1.0f / l_run;
    float* op = out + (size_t)(bh * Sdim + kkw + l31) * Ddim;
#pragma unroll
    for (int db = 0; db < 2; db++) {
#pragma unroll
        for (int g = 0; g < 4; g++) {
            f32x4 st;
#pragma unroll
            for (int q = 0; q < 4; q++)
                st[q] = (db ? accO1[g * 4 + q] : accO0[g * 4 + q]) * inv;
            *(f32x4*)(op + db * 32 + 8 * g + 4 * hi) = st;
        }
    }
}

// ---------------------------------------------------------------- launch
extern "C" void kernel_launch(void* const* d_in, const int* in_sizes, int n_in,
                              void* d_out, int out_size, void* d_ws, size_t ws_size,
                              hipStream_t stream) {
    const float* x    = (const float*)d_in[0];
    const int*   xraw = (const int*)d_in[1];
    const float* Wq   = (const float*)d_in[2];
    const float* bq   = (const float*)d_in[3];
    const float* Wk   = (const float*)d_in[4];
    const float* bk   = (const float*)d_in[5];
    const float* Wv   = (const float*)d_in[6];
    const float* bv   = (const float*)d_in[7];
    float* out = (float*)d_out;
    char* ws = (char*)d_ws;

    short* Xb    = (short*)(ws);                       // 16 MB
    short* Qbuf  = (short*)(ws + (size_t)16777216);    // 16 MB
    short* Kbuf  = (short*)(ws + (size_t)33554432);    // 16 MB
    short* VtG   = (short*)(ws + (size_t)50331648);    // 16 MB (per-head transposed V)
    short* Wqb   = (short*)(ws + (size_t)67108864);    // 2 MB
    short* Wkb   = (short*)(ws + (size_t)69206016);    // 2 MB
    short* Wvb   = (short*)(ws + (size_t)71303168);    // 2 MB
    float* maskf = (float*)(ws + (size_t)73400320);    // 32 KB

    const int nX4 = (Bdim * Sdim * Edim) / 4;
    const int nW4 = (Edim * Edim) / 4;

    cast_f32_bf16<<<(nX4 + 255) / 256, 256, 0, stream>>>(x, Xb, nX4);
    cast_f32_bf16<<<(nW4 + 255) / 256, 256, 0, stream>>>(Wq, Wqb, nW4);
    cast_f32_bf16<<<(nW4 + 255) / 256, 256, 0, stream>>>(Wk, Wkb, nW4);
    cast_f32_bf16<<<(nW4 + 255) / 256, 256, 0, stream>>>(Wv, Wvb, nW4);
    build_mask<<<(Bdim * Sdim) / 256, 256, 0, stream>>>(xraw, maskf);

    dim3 ggrid(64, 8);
    gemm_nt_bf16<0><<<ggrid, 256, 0, stream>>>(Xb, Wqb, bq, Qbuf, Bdim * Sdim, Edim, Edim);
    gemm_nt_bf16<0><<<ggrid, 256, 0, stream>>>(Xb, Wkb, bk, Kbuf, Bdim * Sdim, Edim, Edim);
    gemm_nt_bf16<1><<<ggrid, 256, 0, stream>>>(Xb, Wvb, bv, VtG, Bdim * Sdim, Edim, Edim);

    dim3 agrid(Sdim / 256, Bdim * Hdim);
    attn_fwd2<<<agrid, 512, 0, stream>>>(Qbuf, Kbuf, VtG, maskf, out);
}